// Round 12
// baseline (390.693 us; speedup 1.0000x reference)
//
#include <hip/hip_runtime.h>

#define NCONE 8
#define NDIM 24          // NC*3
#define PGD_ITERS 100
#define BATCH 65536
#define BLOCKT 256       // 1 elem/thread; 1024 waves = 1 wave/SIMD chip-wide
#define POW_ITERS 48
#define NPAIR 150        // 300 upper-triangle entries (row-major), fp16 x2/word

typedef _Float16 half2v __attribute__((ext_vector_type(2)));

__device__ __forceinline__ float fast_rsq(float x) { return __builtin_amdgcn_rsqf(x); }

// Row-major upper-triangle u -> (i,j): row i holds entries (i,i)..(i,23).
// Used ONLY in the (rolled, once-per-launch) pack loop — never in the hot body.
__device__ __forceinline__ int r2i(int u) {
    int i = 0;
    while (u >= NDIM - i) { u -= NDIM - i; ++i; }
    return i;
}
__device__ __forceinline__ int r2j(int u) {
    int i = 0;
    while (u >= NDIM - i) { u -= NDIM - i; ++i; }
    return i + u;
}

// SOC projection, rsqrt-only form (validated R7-R11: absmax 0.031).
__device__ __forceinline__ void soc_proj(float& t, float& x0, float& x1) {
    float n2  = fmaf(x0, x0, x1 * x1);
    float n2s = fmaxf(n2, 1e-30f);
    float rsq = fast_rsq(n2s);
    float n   = n2s * rsq;
    float coef = 0.5f * (t + n);
    float sc   = coef * rsq;
    bool inside = (n <= t);
    bool below  = (n <= -t);
    float tn = inside ? t    : (below ? 0.0f : coef);
    float s  = inside ? 1.0f : (below ? 0.0f : sc);
    t = tn; x0 *= s; x1 *= s;
}

// g(f32) += li(f32) * f16-half of pk — one full-rate VALU op (validated R6+).
#define FMA_MIX_LO(g_, li_, pk_)                                               \
    asm("v_fma_mix_f32 %0, %1, %2, %0 op_sel:[0,0,0] op_sel_hi:[0,1,0]"        \
        : "+v"(g_) : "v"(li_), "v"(pk_))
#define FMA_MIX_HI(g_, li_, pk_)                                               \
    asm("v_fma_mix_f32 %0, %1, %2, %0 op_sel:[0,1,0] op_sel_hi:[0,1,0]"        \
        : "+v"(g_) : "v"(li_), "v"(pk_))

// Word emitters: one packed word = triangle entries (2k, 2k+1).
// WOO: both off-diag; WDO: lo diag, hi off; WOD: lo off, hi diag.
// All g/l indices are LITERALS -> immune to unroll/SROA bail-out (R9 lesson).
#define WOO(pk, i0, j0, i1, j1)                                                \
    FMA_MIX_LO(g[j0], l[i0], pk); FMA_MIX_LO(g[i0], l[j0], pk);                \
    FMA_MIX_HI(g[j1], l[i1], pk); FMA_MIX_HI(g[i1], l[j1], pk)
#define WDO(pk, a, i1, j1)                                                     \
    FMA_MIX_LO(g[a], l[a], pk);                                                \
    FMA_MIX_HI(g[j1], l[i1], pk); FMA_MIX_HI(g[i1], l[j1], pk)
#define WOD(pk, i0, j0, b)                                                     \
    FMA_MIX_LO(g[j0], l[i0], pk); FMA_MIX_LO(g[i0], l[j0], pk);                \
    FMA_MIX_HI(g[b], l[b], pk)

// ---------------------------------------------------------------------------
// Fused kernel, v12.
//
// History: R1 LICM spill | R2 LDS fp32 349us | R4 SMEM 878us | R5-R8
// register-resident P: AGPR shuttle 304us / scratch 14ms | R9 triangle w/
// index-function targets + dual acc: unroll bail -> dynamic private indexing
// -> scratch 13.7ms | R11 fp16 full-P, literal targets: 224us CLEAN,
// LDS-bound (72 b128/wave-iter = 3456 cyc/CU-iter of 5376 wall).
//
// v12 = R11 with the symmetric triangle (300 fp16 = 150 words): 37 b128 +
// 1 b64 LDS reads per wave-iter (was 72). The walk is STRAIGHT-LINE with
// hand-enumerated literal (i,j) pairs — no inner loops, no index functions,
// single accumulator g — the exact properties that kept R11 off the scratch
// cliff. Same 576 v_fma_mix (mirror reuse). LDS/CU-iter 1824 cyc; VALU
// ~1600-3200 cyc/SIMD-iter becomes the binding pipe. Predict 110-160us.
// ---------------------------------------------------------------------------
__global__ __launch_bounds__(BLOCKT, 1) void pgd_fused(const float* __restrict__ P,
                                                       const float* __restrict__ q,
                                                       float* __restrict__ out) {
    __shared__ __align__(16) float sP[NDIM * NDIM];   // fp32 staging (pow-iter)
    __shared__ __align__(16) unsigned sTri[NPAIR];    // fp16-pair triangle, row-major
    __shared__ float sQ[BLOCKT * (NDIM + 1)];         // coalescing buffer, stride 25

    const int tid  = threadIdx.x;
    const int base = blockIdx.x * (BLOCKT * NDIM);

    for (int i = tid; i < NDIM * NDIM; i += BLOCKT)
        sP[i] = P[i];
    for (int idx = tid; idx < BLOCKT * NDIM; idx += BLOCKT) {
        int r = idx / NDIM;
        int c = idx - r * NDIM;
        sQ[r * (NDIM + 1) + c] = q[base + idx];
    }
    __syncthreads();

    // --- pack upper triangle (row-major) as fp16 pairs (strided: R10 lesson) ---
    for (int w = tid; w < NPAIR; w += BLOCKT) {
        half2v hv;
        hv[0] = (_Float16)sP[r2i(2 * w) * NDIM + r2j(2 * w)];
        hv[1] = (_Float16)sP[r2i(2 * w + 1) * NDIM + r2j(2 * w + 1)];
        sTri[w] = __builtin_bit_cast(unsigned, hv);
    }

    // --- step = 1/lambda_max(P): per-wave power iteration + Rayleigh ---
    // (zero inter-block state — R2's graph-replay divergence lesson)
    const int lane = tid & 63;
    float step;
    {
        float p[NDIM];
#pragma unroll
        for (int j = 0; j < NDIM; ++j)
            p[j] = (lane < NDIM) ? sP[lane * NDIM + j] : 0.0f;
        float v = (lane < NDIM) ? (1.0f + 0.01f * (float)lane) : 0.0f;

        for (int it = 0; it < POW_ITERS; ++it) {
            float w = 0.0f;
#pragma unroll
            for (int j = 0; j < NDIM; ++j)
                w = fmaf(p[j], __shfl(v, j, 64), w);
            float n2 = w * w;
#pragma unroll
            for (int off = 32; off >= 1; off >>= 1)
                n2 += __shfl_xor(n2, off, 64);
            v = w * rsqrtf(n2);
        }
        float w = 0.0f;
#pragma unroll
        for (int j = 0; j < NDIM; ++j)
            w = fmaf(p[j], __shfl(v, j, 64), w);
        float num = v * w;
        float den = v * v;
#pragma unroll
        for (int off = 32; off >= 1; off >>= 1) {
            num += __shfl_xor(num, off, 64);
            den += __shfl_xor(den, off, 64);
        }
        step = den / num;   // identical on every lane/wave/block
    }
    __syncthreads();        // sTri visible to all waves

    // --- per-thread state ---
    float lq[NDIM], l[NDIM];
#pragma unroll
    for (int j = 0; j < NDIM; ++j) {
        lq[j] = sQ[tid * (NDIM + 1) + j];
        l[j]  = 0.0f;
    }

    const uint4* sT4 = (const uint4*)sTri;
    const uint2* sT2 = (const uint2*)sTri;

#pragma clang loop unroll(disable)
    for (int it = 0; it < PGD_ITERS; ++it) {
        // Keep the (loop-invariant) triangle reads inside this iteration —
        // defeats LICM register blowup (R1/R2/R11-proven).
        asm volatile("" ::: "memory");

        float g[NDIM];
#pragma unroll
        for (int j = 0; j < NDIM; ++j)
            g[j] = lq[j];

        // g += P l — symmetric triangle walk, straight-line, literal indices.
        uint4 t;
        t = sT4[0];                                   // words 0-3
        WDO(t.x, 0, 0, 1);  WOO(t.y, 0, 2, 0, 3);
        WOO(t.z, 0, 4, 0, 5);  WOO(t.w, 0, 6, 0, 7);
        t = sT4[1];                                   // words 4-7
        WOO(t.x, 0, 8, 0, 9);  WOO(t.y, 0, 10, 0, 11);
        WOO(t.z, 0, 12, 0, 13);  WOO(t.w, 0, 14, 0, 15);
        t = sT4[2];                                   // words 8-11
        WOO(t.x, 0, 16, 0, 17);  WOO(t.y, 0, 18, 0, 19);
        WOO(t.z, 0, 20, 0, 21);  WOO(t.w, 0, 22, 0, 23);
        t = sT4[3];                                   // words 12-15
        WDO(t.x, 1, 1, 2);  WOO(t.y, 1, 3, 1, 4);
        WOO(t.z, 1, 5, 1, 6);  WOO(t.w, 1, 7, 1, 8);
        t = sT4[4];                                   // words 16-19
        WOO(t.x, 1, 9, 1, 10);  WOO(t.y, 1, 11, 1, 12);
        WOO(t.z, 1, 13, 1, 14);  WOO(t.w, 1, 15, 1, 16);
        t = sT4[5];                                   // words 20-23
        WOO(t.x, 1, 17, 1, 18);  WOO(t.y, 1, 19, 1, 20);
        WOO(t.z, 1, 21, 1, 22);  WOD(t.w, 1, 23, 2);
        t = sT4[6];                                   // words 24-27
        WOO(t.x, 2, 3, 2, 4);  WOO(t.y, 2, 5, 2, 6);
        WOO(t.z, 2, 7, 2, 8);  WOO(t.w, 2, 9, 2, 10);
        t = sT4[7];                                   // words 28-31
        WOO(t.x, 2, 11, 2, 12);  WOO(t.y, 2, 13, 2, 14);
        WOO(t.z, 2, 15, 2, 16);  WOO(t.w, 2, 17, 2, 18);
        t = sT4[8];                                   // words 32-35
        WOO(t.x, 2, 19, 2, 20);  WOO(t.y, 2, 21, 2, 22);
        WOD(t.z, 2, 23, 3);  WOO(t.w, 3, 4, 3, 5);
        t = sT4[9];                                   // words 36-39
        WOO(t.x, 3, 6, 3, 7);  WOO(t.y, 3, 8, 3, 9);
        WOO(t.z, 3, 10, 3, 11);  WOO(t.w, 3, 12, 3, 13);
        t = sT4[10];                                  // words 40-43
        WOO(t.x, 3, 14, 3, 15);  WOO(t.y, 3, 16, 3, 17);
        WOO(t.z, 3, 18, 3, 19);  WOO(t.w, 3, 20, 3, 21);
        t = sT4[11];                                  // words 44-47
        WOO(t.x, 3, 22, 3, 23);  WDO(t.y, 4, 4, 5);
        WOO(t.z, 4, 6, 4, 7);  WOO(t.w, 4, 8, 4, 9);
        t = sT4[12];                                  // words 48-51
        WOO(t.x, 4, 10, 4, 11);  WOO(t.y, 4, 12, 4, 13);
        WOO(t.z, 4, 14, 4, 15);  WOO(t.w, 4, 16, 4, 17);
        t = sT4[13];                                  // words 52-55
        WOO(t.x, 4, 18, 4, 19);  WOO(t.y, 4, 20, 4, 21);
        WOO(t.z, 4, 22, 4, 23);  WDO(t.w, 5, 5, 6);
        t = sT4[14];                                  // words 56-59
        WOO(t.x, 5, 7, 5, 8);  WOO(t.y, 5, 9, 5, 10);
        WOO(t.z, 5, 11, 5, 12);  WOO(t.w, 5, 13, 5, 14);
        t = sT4[15];                                  // words 60-63
        WOO(t.x, 5, 15, 5, 16);  WOO(t.y, 5, 17, 5, 18);
        WOO(t.z, 5, 19, 5, 20);  WOO(t.w, 5, 21, 5, 22);
        t = sT4[16];                                  // words 64-67
        WOD(t.x, 5, 23, 6);  WOO(t.y, 6, 7, 6, 8);
        WOO(t.z, 6, 9, 6, 10);  WOO(t.w, 6, 11, 6, 12);
        t = sT4[17];                                  // words 68-71
        WOO(t.x, 6, 13, 6, 14);  WOO(t.y, 6, 15, 6, 16);
        WOO(t.z, 6, 17, 6, 18);  WOO(t.w, 6, 19, 6, 20);
        t = sT4[18];                                  // words 72-75
        WOO(t.x, 6, 21, 6, 22);  WOD(t.y, 6, 23, 7);
        WOO(t.z, 7, 8, 7, 9);  WOO(t.w, 7, 10, 7, 11);
        t = sT4[19];                                  // words 76-79
        WOO(t.x, 7, 12, 7, 13);  WOO(t.y, 7, 14, 7, 15);
        WOO(t.z, 7, 16, 7, 17);  WOO(t.w, 7, 18, 7, 19);
        t = sT4[20];                                  // words 80-83
        WOO(t.x, 7, 20, 7, 21);  WOO(t.y, 7, 22, 7, 23);
        WDO(t.z, 8, 8, 9);  WOO(t.w, 8, 10, 8, 11);
        t = sT4[21];                                  // words 84-87
        WOO(t.x, 8, 12, 8, 13);  WOO(t.y, 8, 14, 8, 15);
        WOO(t.z, 8, 16, 8, 17);  WOO(t.w, 8, 18, 8, 19);
        t = sT4[22];                                  // words 88-91
        WOO(t.x, 8, 20, 8, 21);  WOO(t.y, 8, 22, 8, 23);
        WDO(t.z, 9, 9, 10);  WOO(t.w, 9, 11, 9, 12);
        t = sT4[23];                                  // words 92-95
        WOO(t.x, 9, 13, 9, 14);  WOO(t.y, 9, 15, 9, 16);
        WOO(t.z, 9, 17, 9, 18);  WOO(t.w, 9, 19, 9, 20);
        t = sT4[24];                                  // words 96-99
        WOO(t.x, 9, 21, 9, 22);  WOD(t.y, 9, 23, 10);
        WOO(t.z, 10, 11, 10, 12);  WOO(t.w, 10, 13, 10, 14);
        t = sT4[25];                                  // words 100-103
        WOO(t.x, 10, 15, 10, 16);  WOO(t.y, 10, 17, 10, 18);
        WOO(t.z, 10, 19, 10, 20);  WOO(t.w, 10, 21, 10, 22);
        t = sT4[26];                                  // words 104-107
        WOD(t.x, 10, 23, 11);  WOO(t.y, 11, 12, 11, 13);
        WOO(t.z, 11, 14, 11, 15);  WOO(t.w, 11, 16, 11, 17);
        t = sT4[27];                                  // words 108-111
        WOO(t.x, 11, 18, 11, 19);  WOO(t.y, 11, 20, 11, 21);
        WOO(t.z, 11, 22, 11, 23);  WDO(t.w, 12, 12, 13);
        t = sT4[28];                                  // words 112-115
        WOO(t.x, 12, 14, 12, 15);  WOO(t.y, 12, 16, 12, 17);
        WOO(t.z, 12, 18, 12, 19);  WOO(t.w, 12, 20, 12, 21);
        t = sT4[29];                                  // words 116-119
        WOO(t.x, 12, 22, 12, 23);  WDO(t.y, 13, 13, 14);
        WOO(t.z, 13, 15, 13, 16);  WOO(t.w, 13, 17, 13, 18);
        t = sT4[30];                                  // words 120-123
        WOO(t.x, 13, 19, 13, 20);  WOO(t.y, 13, 21, 13, 22);
        WOD(t.z, 13, 23, 14);  WOO(t.w, 14, 15, 14, 16);
        t = sT4[31];                                  // words 124-127
        WOO(t.x, 14, 17, 14, 18);  WOO(t.y, 14, 19, 14, 20);
        WOO(t.z, 14, 21, 14, 22);  WOD(t.w, 14, 23, 15);
        t = sT4[32];                                  // words 128-131
        WOO(t.x, 15, 16, 15, 17);  WOO(t.y, 15, 18, 15, 19);
        WOO(t.z, 15, 20, 15, 21);  WOO(t.w, 15, 22, 15, 23);
        t = sT4[33];                                  // words 132-135
        WDO(t.x, 16, 16, 17);  WOO(t.y, 16, 18, 16, 19);
        WOO(t.z, 16, 20, 16, 21);  WOO(t.w, 16, 22, 16, 23);
        t = sT4[34];                                  // words 136-139
        WDO(t.x, 17, 17, 18);  WOO(t.y, 17, 19, 17, 20);
        WOO(t.z, 17, 21, 17, 22);  WOD(t.w, 17, 23, 18);
        t = sT4[35];                                  // words 140-143
        WOO(t.x, 18, 19, 18, 20);  WOO(t.y, 18, 21, 18, 22);
        WOD(t.z, 18, 23, 19);  WOO(t.w, 19, 20, 19, 21);
        t = sT4[36];                                  // words 144-147
        WOO(t.x, 19, 22, 19, 23);  WDO(t.y, 20, 20, 21);
        WOO(t.z, 20, 22, 20, 23);  WDO(t.w, 21, 21, 22);
        uint2 t2 = sT2[74];                           // words 148-149
        WOD(t2.x, 21, 23, 22);  WOD(t2.y, 22, 23, 23);

        // y = l - step*g
#pragma unroll
        for (int j = 0; j < NDIM; ++j)
            g[j] = fmaf(-step, g[j], l[j]);

        // project onto product of 8 SOCs
#pragma unroll
        for (int c = 0; c < NCONE; ++c)
            soc_proj(g[c], g[NCONE + 2 * c], g[NCONE + 2 * c + 1]);

#pragma unroll
        for (int j = 0; j < NDIM; ++j)
            l[j] = g[j];
    }

    // --- coalesced store through padded LDS ---
    __syncthreads();
#pragma unroll
    for (int j = 0; j < NDIM; ++j)
        sQ[tid * (NDIM + 1) + j] = l[j];
    __syncthreads();
    for (int idx = tid; idx < BLOCKT * NDIM; idx += BLOCKT) {
        int r = idx / NDIM;
        int c = idx - r * NDIM;
        out[base + idx] = sQ[r * (NDIM + 1) + c];
    }
}

extern "C" void kernel_launch(void* const* d_in, const int* in_sizes, int n_in,
                              void* d_out, int out_size, void* d_ws, size_t ws_size,
                              hipStream_t stream) {
    const float* P = (const float*)d_in[0];   // (1, 24, 24) fp32
    const float* q = (const float*)d_in[1];   // (65536, 24, 1) fp32
    float* out     = (float*)d_out;           // (65536, 24) fp32
    (void)d_ws; (void)ws_size;

    pgd_fused<<<BATCH / BLOCKT, BLOCKT, 0, stream>>>(P, q, out);
}

// Round 13
// 353.975 us; speedup vs baseline: 1.1037x; 1.1037x over previous
//
#include <hip/hip_runtime.h>

#define NCONE 8
#define NDIM 24          // NC*3
#define PGD_ITERS 100
#define BATCH 65536
#define BLOCKT 256       // 1 elem/thread; 1024 waves = 1 wave/SIMD chip-wide
#define POW_ITERS 48
#define NPAIR 150        // 300 upper-triangle entries (BAND-major), fp16 x2/word

typedef _Float16 half2v __attribute__((ext_vector_type(2)));

__device__ __forceinline__ float fast_rsq(float x) { return __builtin_amdgcn_rsqf(x); }

// Band-major upper-triangle u -> (i,j): d = j-i ascending, i ascending.
// Used ONLY in the (rolled, once-per-launch) pack loop — never in the hot body.
__device__ __forceinline__ int b2i(int u) {
    int d = 0;
    while (u >= NDIM - d) { u -= NDIM - d; ++d; }
    return u;
}
__device__ __forceinline__ int b2j(int u) {
    int d = 0;
    while (u >= NDIM - d) { u -= NDIM - d; ++d; }
    return u + d;
}

// SOC projection, rsqrt-only form (validated R7-R12: absmax 0.031).
__device__ __forceinline__ void soc_proj(float& t, float& x0, float& x1) {
    float n2  = fmaf(x0, x0, x1 * x1);
    float n2s = fmaxf(n2, 1e-30f);
    float rsq = fast_rsq(n2s);
    float n   = n2s * rsq;
    float coef = 0.5f * (t + n);
    float sc   = coef * rsq;
    bool inside = (n <= t);
    bool below  = (n <= -t);
    float tn = inside ? t    : (below ? 0.0f : coef);
    float s  = inside ? 1.0f : (below ? 0.0f : sc);
    t = tn; x0 *= s; x1 *= s;
}

// g(f32) += li(f32) * f16-half of pk — one full-rate VALU op (validated R6+).
#define FMA_MIX_LO(g_, li_, pk_)                                               \
    asm("v_fma_mix_f32 %0, %1, %2, %0 op_sel:[0,0,0] op_sel_hi:[0,1,0]"        \
        : "+v"(g_) : "v"(li_), "v"(pk_))
#define FMA_MIX_HI(g_, li_, pk_)                                               \
    asm("v_fma_mix_f32 %0, %1, %2, %0 op_sel:[0,1,0] op_sel_hi:[0,1,0]"        \
        : "+v"(g_) : "v"(li_), "v"(pk_))

// Word emitters (all indices LITERAL — R9/R11 lesson).
// DD: both halves diagonal. OO: both halves off-diagonal (+ mirror).
#define DD(pk, a, b)                                                           \
    FMA_MIX_LO(g[a], l[a], pk); FMA_MIX_HI(g[b], l[b], pk)
#define OO(pk, i0, j0, i1, j1)                                                 \
    FMA_MIX_LO(g[j0], l[i0], pk); FMA_MIX_LO(g[i0], l[j0], pk);                \
    FMA_MIX_HI(g[j1], l[i1], pk); FMA_MIX_HI(g[i1], l[j1], pk)

// ---------------------------------------------------------------------------
// Fused kernel, v13.
//
// History: R2 LDS fp32 349us | R5-R8 register-resident P: AGPR shuttle 304us
// / scratch 14ms | R9 triangle w/ index functions: scratch 13.7ms | R11 fp16
// full-P literal walk: 224us CLEAN (LDS 72 b128 + no chains) | R12 row-major
// triangle: 343us — LDS halved but the mirror RMW chain on g[i] (23 deep,
// 2-inst spacing) exposed ~5300 stall cyc/iter at 1 wave/SIMD.
//
// v13 = R12's exact ingredients in BAND-MAJOR order: within band d, writes
// to the same g[j] are 2d+1 >= 3 insts apart (>= FMA latency); diagonal band
// touches each g once. Straight-line, literal indices, single accumulator.
// 38 LDS reads + ~600 fma_mix, stall-free -> predict 120-180us.
// ---------------------------------------------------------------------------
__global__ __launch_bounds__(BLOCKT, 1) void pgd_fused(const float* __restrict__ P,
                                                       const float* __restrict__ q,
                                                       float* __restrict__ out) {
    __shared__ __align__(16) float sP[NDIM * NDIM];   // fp32 staging (pow-iter)
    __shared__ __align__(16) unsigned sTri[NPAIR + 2];// fp16-pair triangle, band-major
    __shared__ float sQ[BLOCKT * (NDIM + 1)];         // coalescing buffer, stride 25

    const int tid  = threadIdx.x;
    const int base = blockIdx.x * (BLOCKT * NDIM);

    for (int i = tid; i < NDIM * NDIM; i += BLOCKT)
        sP[i] = P[i];
    for (int idx = tid; idx < BLOCKT * NDIM; idx += BLOCKT) {
        int r = idx / NDIM;
        int c = idx - r * NDIM;
        sQ[r * (NDIM + 1) + c] = q[base + idx];
    }
    __syncthreads();

    // --- pack upper triangle (BAND-major) as fp16 pairs (strided: R10 lesson) ---
    for (int w = tid; w < NPAIR; w += BLOCKT) {
        half2v hv;
        hv[0] = (_Float16)sP[b2i(2 * w) * NDIM + b2j(2 * w)];
        hv[1] = (_Float16)sP[b2i(2 * w + 1) * NDIM + b2j(2 * w + 1)];
        sTri[w] = __builtin_bit_cast(unsigned, hv);
    }

    // --- step = 1/lambda_max(P): per-wave power iteration + Rayleigh ---
    // (zero inter-block state — R2's graph-replay divergence lesson)
    const int lane = tid & 63;
    float step;
    {
        float p[NDIM];
#pragma unroll
        for (int j = 0; j < NDIM; ++j)
            p[j] = (lane < NDIM) ? sP[lane * NDIM + j] : 0.0f;
        float v = (lane < NDIM) ? (1.0f + 0.01f * (float)lane) : 0.0f;

        for (int it = 0; it < POW_ITERS; ++it) {
            float w = 0.0f;
#pragma unroll
            for (int j = 0; j < NDIM; ++j)
                w = fmaf(p[j], __shfl(v, j, 64), w);
            float n2 = w * w;
#pragma unroll
            for (int off = 32; off >= 1; off >>= 1)
                n2 += __shfl_xor(n2, off, 64);
            v = w * rsqrtf(n2);
        }
        float w = 0.0f;
#pragma unroll
        for (int j = 0; j < NDIM; ++j)
            w = fmaf(p[j], __shfl(v, j, 64), w);
        float num = v * w;
        float den = v * v;
#pragma unroll
        for (int off = 32; off >= 1; off >>= 1) {
            num += __shfl_xor(num, off, 64);
            den += __shfl_xor(den, off, 64);
        }
        step = den / num;   // identical on every lane/wave/block
    }
    __syncthreads();        // sTri visible to all waves

    // --- per-thread state ---
    float lq[NDIM], l[NDIM];
#pragma unroll
    for (int j = 0; j < NDIM; ++j) {
        lq[j] = sQ[tid * (NDIM + 1) + j];
        l[j]  = 0.0f;
    }

    const uint4* sT4 = (const uint4*)sTri;
    const uint2* sT2 = (const uint2*)sTri;

#pragma clang loop unroll(disable)
    for (int it = 0; it < PGD_ITERS; ++it) {
        // Keep the (loop-invariant) triangle reads inside this iteration —
        // defeats LICM register blowup (R1/R2/R11-proven).
        asm volatile("" ::: "memory");

        float g[NDIM];
#pragma unroll
        for (int j = 0; j < NDIM; ++j)
            g[j] = lq[j];

        // g += P l — band-major triangle, straight-line, literal indices.
        uint4 t;
        t = sT4[0];   // diag 0-7
        DD(t.x, 0, 1);   DD(t.y, 2, 3);   DD(t.z, 4, 5);   DD(t.w, 6, 7);
        t = sT4[1];   // diag 8-15
        DD(t.x, 8, 9);   DD(t.y, 10, 11); DD(t.z, 12, 13); DD(t.w, 14, 15);
        t = sT4[2];   // diag 16-23
        DD(t.x, 16, 17); DD(t.y, 18, 19); DD(t.z, 20, 21); DD(t.w, 22, 23);
        t = sT4[3];   // band1
        OO(t.x, 0, 1, 1, 2);    OO(t.y, 2, 3, 3, 4);
        OO(t.z, 4, 5, 5, 6);    OO(t.w, 6, 7, 7, 8);
        t = sT4[4];
        OO(t.x, 8, 9, 9, 10);   OO(t.y, 10, 11, 11, 12);
        OO(t.z, 12, 13, 13, 14);OO(t.w, 14, 15, 15, 16);
        t = sT4[5];
        OO(t.x, 16, 17, 17, 18);OO(t.y, 18, 19, 19, 20);
        OO(t.z, 20, 21, 21, 22);OO(t.w, 22, 23, 0, 2);    // band1 end + band2
        t = sT4[6];
        OO(t.x, 1, 3, 2, 4);    OO(t.y, 3, 5, 4, 6);
        OO(t.z, 5, 7, 6, 8);    OO(t.w, 7, 9, 8, 10);
        t = sT4[7];
        OO(t.x, 9, 11, 10, 12); OO(t.y, 11, 13, 12, 14);
        OO(t.z, 13, 15, 14, 16);OO(t.w, 15, 17, 16, 18);
        t = sT4[8];
        OO(t.x, 17, 19, 18, 20);OO(t.y, 19, 21, 20, 22);
        OO(t.z, 21, 23, 0, 3);  OO(t.w, 1, 4, 2, 5);      // band2 end + band3
        t = sT4[9];
        OO(t.x, 3, 6, 4, 7);    OO(t.y, 5, 8, 6, 9);
        OO(t.z, 7, 10, 8, 11);  OO(t.w, 9, 12, 10, 13);
        t = sT4[10];
        OO(t.x, 11, 14, 12, 15);OO(t.y, 13, 16, 14, 17);
        OO(t.z, 15, 18, 16, 19);OO(t.w, 17, 20, 18, 21);
        t = sT4[11];
        OO(t.x, 19, 22, 20, 23);OO(t.y, 0, 4, 1, 5);      // band3 end + band4
        OO(t.z, 2, 6, 3, 7);    OO(t.w, 4, 8, 5, 9);
        t = sT4[12];
        OO(t.x, 6, 10, 7, 11);  OO(t.y, 8, 12, 9, 13);
        OO(t.z, 10, 14, 11, 15);OO(t.w, 12, 16, 13, 17);
        t = sT4[13];
        OO(t.x, 14, 18, 15, 19);OO(t.y, 16, 20, 17, 21);
        OO(t.z, 18, 22, 19, 23);OO(t.w, 0, 5, 1, 6);      // band4 end + band5
        t = sT4[14];
        OO(t.x, 2, 7, 3, 8);    OO(t.y, 4, 9, 5, 10);
        OO(t.z, 6, 11, 7, 12);  OO(t.w, 8, 13, 9, 14);
        t = sT4[15];
        OO(t.x, 10, 15, 11, 16);OO(t.y, 12, 17, 13, 18);
        OO(t.z, 14, 19, 15, 20);OO(t.w, 16, 21, 17, 22);
        t = sT4[16];
        OO(t.x, 18, 23, 0, 6);  OO(t.y, 1, 7, 2, 8);      // band5 end + band6
        OO(t.z, 3, 9, 4, 10);   OO(t.w, 5, 11, 6, 12);
        t = sT4[17];
        OO(t.x, 7, 13, 8, 14);  OO(t.y, 9, 15, 10, 16);
        OO(t.z, 11, 17, 12, 18);OO(t.w, 13, 19, 14, 20);
        t = sT4[18];
        OO(t.x, 15, 21, 16, 22);OO(t.y, 17, 23, 0, 7);    // band6 end + band7
        OO(t.z, 1, 8, 2, 9);    OO(t.w, 3, 10, 4, 11);
        t = sT4[19];
        OO(t.x, 5, 12, 6, 13);  OO(t.y, 7, 14, 8, 15);
        OO(t.z, 9, 16, 10, 17); OO(t.w, 11, 18, 12, 19);
        t = sT4[20];
        OO(t.x, 13, 20, 14, 21);OO(t.y, 15, 22, 16, 23);
        OO(t.z, 0, 8, 1, 9);    OO(t.w, 2, 10, 3, 11);    // band8
        t = sT4[21];
        OO(t.x, 4, 12, 5, 13);  OO(t.y, 6, 14, 7, 15);
        OO(t.z, 8, 16, 9, 17);  OO(t.w, 10, 18, 11, 19);
        t = sT4[22];
        OO(t.x, 12, 20, 13, 21);OO(t.y, 14, 22, 15, 23);
        OO(t.z, 0, 9, 1, 10);   OO(t.w, 2, 11, 3, 12);    // band9
        t = sT4[23];
        OO(t.x, 4, 13, 5, 14);  OO(t.y, 6, 15, 7, 16);
        OO(t.z, 8, 17, 9, 18);  OO(t.w, 10, 19, 11, 20);
        t = sT4[24];
        OO(t.x, 12, 21, 13, 22);OO(t.y, 14, 23, 0, 10);   // band9 end + band10
        OO(t.z, 1, 11, 2, 12);  OO(t.w, 3, 13, 4, 14);
        t = sT4[25];
        OO(t.x, 5, 15, 6, 16);  OO(t.y, 7, 17, 8, 18);
        OO(t.z, 9, 19, 10, 20); OO(t.w, 11, 21, 12, 22);
        t = sT4[26];
        OO(t.x, 13, 23, 0, 11); OO(t.y, 1, 12, 2, 13);    // band10 end + band11
        OO(t.z, 3, 14, 4, 15);  OO(t.w, 5, 16, 6, 17);
        t = sT4[27];
        OO(t.x, 7, 18, 8, 19);  OO(t.y, 9, 20, 10, 21);
        OO(t.z, 11, 22, 12, 23);OO(t.w, 0, 12, 1, 13);    // band11 end + band12
        t = sT4[28];
        OO(t.x, 2, 14, 3, 15);  OO(t.y, 4, 16, 5, 17);
        OO(t.z, 6, 18, 7, 19);  OO(t.w, 8, 20, 9, 21);
        t = sT4[29];
        OO(t.x, 10, 22, 11, 23);OO(t.y, 0, 13, 1, 14);    // band12 end + band13
        OO(t.z, 2, 15, 3, 16);  OO(t.w, 4, 17, 5, 18);
        t = sT4[30];
        OO(t.x, 6, 19, 7, 20);  OO(t.y, 8, 21, 9, 22);
        OO(t.z, 10, 23, 0, 14); OO(t.w, 1, 15, 2, 16);    // band13 end + band14
        t = sT4[31];
        OO(t.x, 3, 17, 4, 18);  OO(t.y, 5, 19, 6, 20);
        OO(t.z, 7, 21, 8, 22);  OO(t.w, 9, 23, 0, 15);    // band14 end + band15
        t = sT4[32];
        OO(t.x, 1, 16, 2, 17);  OO(t.y, 3, 18, 4, 19);
        OO(t.z, 5, 20, 6, 21);  OO(t.w, 7, 22, 8, 23);
        t = sT4[33];
        OO(t.x, 0, 16, 1, 17);  OO(t.y, 2, 18, 3, 19);    // band16
        OO(t.z, 4, 20, 5, 21);  OO(t.w, 6, 22, 7, 23);
        t = sT4[34];
        OO(t.x, 0, 17, 1, 18);  OO(t.y, 2, 19, 3, 20);    // band17
        OO(t.z, 4, 21, 5, 22);  OO(t.w, 6, 23, 0, 18);    // band17 end + band18
        t = sT4[35];
        OO(t.x, 1, 19, 2, 20);  OO(t.y, 3, 21, 4, 22);
        OO(t.z, 5, 23, 0, 19);  OO(t.w, 1, 20, 2, 21);    // band18 end + band19
        t = sT4[36];
        OO(t.x, 3, 22, 4, 23);  OO(t.y, 0, 20, 1, 21);    // band19 end + band20
        OO(t.z, 2, 22, 3, 23);  OO(t.w, 0, 21, 1, 22);    // band20 end + band21
        uint2 t2 = sT2[74];
        OO(t2.x, 2, 23, 0, 22); OO(t2.y, 1, 23, 0, 23);   // bands 21/22/23

        // y = l - step*g
#pragma unroll
        for (int j = 0; j < NDIM; ++j)
            g[j] = fmaf(-step, g[j], l[j]);

        // project onto product of 8 SOCs
#pragma unroll
        for (int c = 0; c < NCONE; ++c)
            soc_proj(g[c], g[NCONE + 2 * c], g[NCONE + 2 * c + 1]);

#pragma unroll
        for (int j = 0; j < NDIM; ++j)
            l[j] = g[j];
    }

    // --- coalesced store through padded LDS ---
    __syncthreads();
#pragma unroll
    for (int j = 0; j < NDIM; ++j)
        sQ[tid * (NDIM + 1) + j] = l[j];
    __syncthreads();
    for (int idx = tid; idx < BLOCKT * NDIM; idx += BLOCKT) {
        int r = idx / NDIM;
        int c = idx - r * NDIM;
        out[base + idx] = sQ[r * (NDIM + 1) + c];
    }
}

extern "C" void kernel_launch(void* const* d_in, const int* in_sizes, int n_in,
                              void* d_out, int out_size, void* d_ws, size_t ws_size,
                              hipStream_t stream) {
    const float* P = (const float*)d_in[0];   // (1, 24, 24) fp32
    const float* q = (const float*)d_in[1];   // (65536, 24, 1) fp32
    float* out     = (float*)d_out;           // (65536, 24) fp32
    (void)d_ws; (void)ws_size;

    pgd_fused<<<BATCH / BLOCKT, BLOCKT, 0, stream>>>(P, q, out);
}

// Round 14
// 244.336 us; speedup vs baseline: 1.5990x; 1.4487x over previous
//
#include <hip/hip_runtime.h>

#define NCONE 8
#define NDIM 24          // NC*3
#define PGD_ITERS 100
#define BATCH 65536
#define BLOCKT 256       // 1 elem/thread; 1024 waves = 1 wave/SIMD chip-wide
#define POW_ITERS 48
#define NPAIR 150        // 300 upper-triangle entries (BAND-major), fp16 x2/word

typedef _Float16 half2v __attribute__((ext_vector_type(2)));

__device__ __forceinline__ float fast_rsq(float x) { return __builtin_amdgcn_rsqf(x); }

// Band-major upper-triangle u -> (i,j): d = j-i ascending, i ascending.
// Used ONLY in the (rolled, once-per-launch) pack loop — never in the hot body.
__device__ __forceinline__ int b2i(int u) {
    int d = 0;
    while (u >= NDIM - d) { u -= NDIM - d; ++d; }
    return u;
}
__device__ __forceinline__ int b2j(int u) {
    int d = 0;
    while (u >= NDIM - d) { u -= NDIM - d; ++d; }
    return u + d;
}

// SOC projection, rsqrt-only form (validated R7-R13: absmax 0.031).
__device__ __forceinline__ void soc_proj(float& t, float& x0, float& x1) {
    float n2  = fmaf(x0, x0, x1 * x1);
    float n2s = fmaxf(n2, 1e-30f);
    float rsq = fast_rsq(n2s);
    float n   = n2s * rsq;
    float coef = 0.5f * (t + n);
    float sc   = coef * rsq;
    bool inside = (n <= t);
    bool below  = (n <= -t);
    float tn = inside ? t    : (below ? 0.0f : coef);
    float s  = inside ? 1.0f : (below ? 0.0f : sc);
    t = tn; x0 *= s; x1 *= s;
}

// g(f32) += li(f32) * f16-half of pk — one full-rate VALU op (validated R6+).
#define FMA_MIX_LO(g_, li_, pk_)                                               \
    asm("v_fma_mix_f32 %0, %1, %2, %0 op_sel:[0,0,0] op_sel_hi:[0,1,0]"        \
        : "+v"(g_) : "v"(li_), "v"(pk_))
#define FMA_MIX_HI(g_, li_, pk_)                                               \
    asm("v_fma_mix_f32 %0, %1, %2, %0 op_sel:[0,1,0] op_sel_hi:[0,1,0]"        \
        : "+v"(g_) : "v"(li_), "v"(pk_))

// Word emitters (all indices LITERAL — R9/R11 lesson).
#define DD(pk, a, b)                                                           \
    FMA_MIX_LO(g[a], l[a], pk); FMA_MIX_HI(g[b], l[b], pk)
#define OO(pk, i0, j0, i1, j1)                                                 \
    FMA_MIX_LO(g[j0], l[i0], pk); FMA_MIX_LO(g[i0], l[j0], pk);                \
    FMA_MIX_HI(g[j1], l[i1], pk); FMA_MIX_HI(g[i1], l[j1], pk)

// ---------------------------------------------------------------------------
// Fused kernel, v14.
//
// History: R11 fp16 full-P 224us | R12 row-major triangle 343us | R13
// band-major triangle 335us. R13 diagnosis: the FMA_MIX inline-asm acts as
// scheduling fences and the triangle words were loaded as SINGLETONS ->
// every ds_read_b128's ~120-150cyc latency fully exposed in program order
// (38 x ~120 ~= 4600 stall cyc/iter at 1 wave/SIMD). R11 was faster only
// because it kept 3 loads in flight per row. The metric that matters is
// EXPOSED LDS LATENCY, not LDS op count.
//
// v14 = R13's exact FMA stream, software-pipelined: 10 chunks of 4 uint4,
// double-buffered A/B — issue chunk k+1's 4 loads back-to-back, consume
// chunk k's 64 FMAs (~128 cyc ~ load latency) while they fly. In-order LDS
// retirement -> fine-grained lgkmcnt waits; asm fences preserve this manual
// schedule exactly. ~110 live VGPRs (plain f32 — not the R5-R8 AGPR bait).
// Predict wall ~3300-3700 cyc/iter -> 135-185us.
// ---------------------------------------------------------------------------
__global__ __launch_bounds__(BLOCKT, 1) void pgd_fused(const float* __restrict__ P,
                                                       const float* __restrict__ q,
                                                       float* __restrict__ out) {
    __shared__ __align__(16) float sP[NDIM * NDIM];   // fp32 staging (pow-iter)
    __shared__ __align__(16) unsigned sTri[NPAIR + 2];// fp16-pair triangle, band-major
    __shared__ float sQ[BLOCKT * (NDIM + 1)];         // coalescing buffer, stride 25

    const int tid  = threadIdx.x;
    const int base = blockIdx.x * (BLOCKT * NDIM);

    for (int i = tid; i < NDIM * NDIM; i += BLOCKT)
        sP[i] = P[i];
    for (int idx = tid; idx < BLOCKT * NDIM; idx += BLOCKT) {
        int r = idx / NDIM;
        int c = idx - r * NDIM;
        sQ[r * (NDIM + 1) + c] = q[base + idx];
    }
    __syncthreads();

    // --- pack upper triangle (BAND-major) as fp16 pairs (strided: R10 lesson) ---
    for (int w = tid; w < NPAIR; w += BLOCKT) {
        half2v hv;
        hv[0] = (_Float16)sP[b2i(2 * w) * NDIM + b2j(2 * w)];
        hv[1] = (_Float16)sP[b2i(2 * w + 1) * NDIM + b2j(2 * w + 1)];
        sTri[w] = __builtin_bit_cast(unsigned, hv);
    }

    // --- step = 1/lambda_max(P): per-wave power iteration + Rayleigh ---
    // (zero inter-block state — R2's graph-replay divergence lesson)
    const int lane = tid & 63;
    float step;
    {
        float p[NDIM];
#pragma unroll
        for (int j = 0; j < NDIM; ++j)
            p[j] = (lane < NDIM) ? sP[lane * NDIM + j] : 0.0f;
        float v = (lane < NDIM) ? (1.0f + 0.01f * (float)lane) : 0.0f;

        for (int it = 0; it < POW_ITERS; ++it) {
            float w = 0.0f;
#pragma unroll
            for (int j = 0; j < NDIM; ++j)
                w = fmaf(p[j], __shfl(v, j, 64), w);
            float n2 = w * w;
#pragma unroll
            for (int off = 32; off >= 1; off >>= 1)
                n2 += __shfl_xor(n2, off, 64);
            v = w * rsqrtf(n2);
        }
        float w = 0.0f;
#pragma unroll
        for (int j = 0; j < NDIM; ++j)
            w = fmaf(p[j], __shfl(v, j, 64), w);
        float num = v * w;
        float den = v * v;
#pragma unroll
        for (int off = 32; off >= 1; off >>= 1) {
            num += __shfl_xor(num, off, 64);
            den += __shfl_xor(den, off, 64);
        }
        step = den / num;   // identical on every lane/wave/block
    }
    __syncthreads();        // sTri visible to all waves

    // --- per-thread state ---
    float lq[NDIM], l[NDIM];
#pragma unroll
    for (int j = 0; j < NDIM; ++j) {
        lq[j] = sQ[tid * (NDIM + 1) + j];
        l[j]  = 0.0f;
    }

    const uint4* sT4 = (const uint4*)sTri;
    const uint2* sT2 = (const uint2*)sTri;

#pragma clang loop unroll(disable)
    for (int it = 0; it < PGD_ITERS; ++it) {
        // Keep the (loop-invariant) triangle reads inside this iteration —
        // defeats LICM register blowup (R1/R2/R11-proven).
        asm volatile("" ::: "memory");

        float g[NDIM];
#pragma unroll
        for (int j = 0; j < NDIM; ++j)
            g[j] = lq[j];

        // ---- software-pipelined band-major triangle walk ----
        uint4 A0 = sT4[0], A1 = sT4[1], A2 = sT4[2], A3 = sT4[3];
        uint4 B0 = sT4[4], B1 = sT4[5], B2 = sT4[6], B3 = sT4[7];

        // consume C0 (words 0-15: diag + band1 start)
        DD(A0.x, 0, 1);   DD(A0.y, 2, 3);   DD(A0.z, 4, 5);   DD(A0.w, 6, 7);
        DD(A1.x, 8, 9);   DD(A1.y, 10, 11); DD(A1.z, 12, 13); DD(A1.w, 14, 15);
        DD(A2.x, 16, 17); DD(A2.y, 18, 19); DD(A2.z, 20, 21); DD(A2.w, 22, 23);
        OO(A3.x, 0, 1, 1, 2);   OO(A3.y, 2, 3, 3, 4);
        OO(A3.z, 4, 5, 5, 6);   OO(A3.w, 6, 7, 7, 8);

        A0 = sT4[8]; A1 = sT4[9]; A2 = sT4[10]; A3 = sT4[11];   // prefetch C2
        // consume C1
        OO(B0.x, 8, 9, 9, 10);    OO(B0.y, 10, 11, 11, 12);
        OO(B0.z, 12, 13, 13, 14); OO(B0.w, 14, 15, 15, 16);
        OO(B1.x, 16, 17, 17, 18); OO(B1.y, 18, 19, 19, 20);
        OO(B1.z, 20, 21, 21, 22); OO(B1.w, 22, 23, 0, 2);
        OO(B2.x, 1, 3, 2, 4);     OO(B2.y, 3, 5, 4, 6);
        OO(B2.z, 5, 7, 6, 8);     OO(B2.w, 7, 9, 8, 10);
        OO(B3.x, 9, 11, 10, 12);  OO(B3.y, 11, 13, 12, 14);
        OO(B3.z, 13, 15, 14, 16); OO(B3.w, 15, 17, 16, 18);

        B0 = sT4[12]; B1 = sT4[13]; B2 = sT4[14]; B3 = sT4[15]; // prefetch C3
        // consume C2
        OO(A0.x, 17, 19, 18, 20); OO(A0.y, 19, 21, 20, 22);
        OO(A0.z, 21, 23, 0, 3);   OO(A0.w, 1, 4, 2, 5);
        OO(A1.x, 3, 6, 4, 7);     OO(A1.y, 5, 8, 6, 9);
        OO(A1.z, 7, 10, 8, 11);   OO(A1.w, 9, 12, 10, 13);
        OO(A2.x, 11, 14, 12, 15); OO(A2.y, 13, 16, 14, 17);
        OO(A2.z, 15, 18, 16, 19); OO(A2.w, 17, 20, 18, 21);
        OO(A3.x, 19, 22, 20, 23); OO(A3.y, 0, 4, 1, 5);
        OO(A3.z, 2, 6, 3, 7);     OO(A3.w, 4, 8, 5, 9);

        A0 = sT4[16]; A1 = sT4[17]; A2 = sT4[18]; A3 = sT4[19]; // prefetch C4
        // consume C3
        OO(B0.x, 6, 10, 7, 11);   OO(B0.y, 8, 12, 9, 13);
        OO(B0.z, 10, 14, 11, 15); OO(B0.w, 12, 16, 13, 17);
        OO(B1.x, 14, 18, 15, 19); OO(B1.y, 16, 20, 17, 21);
        OO(B1.z, 18, 22, 19, 23); OO(B1.w, 0, 5, 1, 6);
        OO(B2.x, 2, 7, 3, 8);     OO(B2.y, 4, 9, 5, 10);
        OO(B2.z, 6, 11, 7, 12);   OO(B2.w, 8, 13, 9, 14);
        OO(B3.x, 10, 15, 11, 16); OO(B3.y, 12, 17, 13, 18);
        OO(B3.z, 14, 19, 15, 20); OO(B3.w, 16, 21, 17, 22);

        B0 = sT4[20]; B1 = sT4[21]; B2 = sT4[22]; B3 = sT4[23]; // prefetch C5
        // consume C4
        OO(A0.x, 18, 23, 0, 6);   OO(A0.y, 1, 7, 2, 8);
        OO(A0.z, 3, 9, 4, 10);    OO(A0.w, 5, 11, 6, 12);
        OO(A1.x, 7, 13, 8, 14);   OO(A1.y, 9, 15, 10, 16);
        OO(A1.z, 11, 17, 12, 18); OO(A1.w, 13, 19, 14, 20);
        OO(A2.x, 15, 21, 16, 22); OO(A2.y, 17, 23, 0, 7);
        OO(A2.z, 1, 8, 2, 9);     OO(A2.w, 3, 10, 4, 11);
        OO(A3.x, 5, 12, 6, 13);   OO(A3.y, 7, 14, 8, 15);
        OO(A3.z, 9, 16, 10, 17);  OO(A3.w, 11, 18, 12, 19);

        A0 = sT4[24]; A1 = sT4[25]; A2 = sT4[26]; A3 = sT4[27]; // prefetch C6
        // consume C5
        OO(B0.x, 13, 20, 14, 21); OO(B0.y, 15, 22, 16, 23);
        OO(B0.z, 0, 8, 1, 9);     OO(B0.w, 2, 10, 3, 11);
        OO(B1.x, 4, 12, 5, 13);   OO(B1.y, 6, 14, 7, 15);
        OO(B1.z, 8, 16, 9, 17);   OO(B1.w, 10, 18, 11, 19);
        OO(B2.x, 12, 20, 13, 21); OO(B2.y, 14, 22, 15, 23);
        OO(B2.z, 0, 9, 1, 10);    OO(B2.w, 2, 11, 3, 12);
        OO(B3.x, 4, 13, 5, 14);   OO(B3.y, 6, 15, 7, 16);
        OO(B3.z, 8, 17, 9, 18);   OO(B3.w, 10, 19, 11, 20);

        B0 = sT4[28]; B1 = sT4[29]; B2 = sT4[30]; B3 = sT4[31]; // prefetch C7
        // consume C6
        OO(A0.x, 12, 21, 13, 22); OO(A0.y, 14, 23, 0, 10);
        OO(A0.z, 1, 11, 2, 12);   OO(A0.w, 3, 13, 4, 14);
        OO(A1.x, 5, 15, 6, 16);   OO(A1.y, 7, 17, 8, 18);
        OO(A1.z, 9, 19, 10, 20);  OO(A1.w, 11, 21, 12, 22);
        OO(A2.x, 13, 23, 0, 11);  OO(A2.y, 1, 12, 2, 13);
        OO(A2.z, 3, 14, 4, 15);   OO(A2.w, 5, 16, 6, 17);
        OO(A3.x, 7, 18, 8, 19);   OO(A3.y, 9, 20, 10, 21);
        OO(A3.z, 11, 22, 12, 23); OO(A3.w, 0, 12, 1, 13);

        A0 = sT4[32]; A1 = sT4[33]; A2 = sT4[34]; A3 = sT4[35]; // prefetch C8
        // consume C7
        OO(B0.x, 2, 14, 3, 15);   OO(B0.y, 4, 16, 5, 17);
        OO(B0.z, 6, 18, 7, 19);   OO(B0.w, 8, 20, 9, 21);
        OO(B1.x, 10, 22, 11, 23); OO(B1.y, 0, 13, 1, 14);
        OO(B1.z, 2, 15, 3, 16);   OO(B1.w, 4, 17, 5, 18);
        OO(B2.x, 6, 19, 7, 20);   OO(B2.y, 8, 21, 9, 22);
        OO(B2.z, 10, 23, 0, 14);  OO(B2.w, 1, 15, 2, 16);
        OO(B3.x, 3, 17, 4, 18);   OO(B3.y, 5, 19, 6, 20);
        OO(B3.z, 7, 21, 8, 22);   OO(B3.w, 9, 23, 0, 15);

        B0 = sT4[36];                                           // prefetch C9
        uint2 B4 = sT2[74];
        // consume C8
        OO(A0.x, 1, 16, 2, 17);   OO(A0.y, 3, 18, 4, 19);
        OO(A0.z, 5, 20, 6, 21);   OO(A0.w, 7, 22, 8, 23);
        OO(A1.x, 0, 16, 1, 17);   OO(A1.y, 2, 18, 3, 19);
        OO(A1.z, 4, 20, 5, 21);   OO(A1.w, 6, 22, 7, 23);
        OO(A2.x, 0, 17, 1, 18);   OO(A2.y, 2, 19, 3, 20);
        OO(A2.z, 4, 21, 5, 22);   OO(A2.w, 6, 23, 0, 18);
        OO(A3.x, 1, 19, 2, 20);   OO(A3.y, 3, 21, 4, 22);
        OO(A3.z, 5, 23, 0, 19);   OO(A3.w, 1, 20, 2, 21);

        // consume C9
        OO(B0.x, 3, 22, 4, 23);   OO(B0.y, 0, 20, 1, 21);
        OO(B0.z, 2, 22, 3, 23);   OO(B0.w, 0, 21, 1, 22);
        OO(B4.x, 2, 23, 0, 22);   OO(B4.y, 1, 23, 0, 23);

        // y = l - step*g
#pragma unroll
        for (int j = 0; j < NDIM; ++j)
            g[j] = fmaf(-step, g[j], l[j]);

        // project onto product of 8 SOCs
#pragma unroll
        for (int c = 0; c < NCONE; ++c)
            soc_proj(g[c], g[NCONE + 2 * c], g[NCONE + 2 * c + 1]);

#pragma unroll
        for (int j = 0; j < NDIM; ++j)
            l[j] = g[j];
    }

    // --- coalesced store through padded LDS ---
    __syncthreads();
#pragma unroll
    for (int j = 0; j < NDIM; ++j)
        sQ[tid * (NDIM + 1) + j] = l[j];
    __syncthreads();
    for (int idx = tid; idx < BLOCKT * NDIM; idx += BLOCKT) {
        int r = idx / NDIM;
        int c = idx - r * NDIM;
        out[base + idx] = sQ[r * (NDIM + 1) + c];
    }
}

extern "C" void kernel_launch(void* const* d_in, const int* in_sizes, int n_in,
                              void* d_out, int out_size, void* d_ws, size_t ws_size,
                              hipStream_t stream) {
    const float* P = (const float*)d_in[0];   // (1, 24, 24) fp32
    const float* q = (const float*)d_in[1];   // (65536, 24, 1) fp32
    float* out     = (float*)d_out;           // (65536, 24) fp32
    (void)d_ws; (void)ws_size;

    pgd_fused<<<BATCH / BLOCKT, BLOCKT, 0, stream>>>(P, q, out);
}

// Round 15
// 162.097 us; speedup vs baseline: 2.4102x; 1.5073x over previous
//
#include <hip/hip_runtime.h>

#define NDIM 24          // NC*3
#define NCONE 8
#define PGD_ITERS 100
#define BATCH 65536
#define BLOCKT 256       // 4 waves/block, 32 elements per wave
#define EPB 128          // elements per block
#define POW_ITERS 48

typedef _Float16 half2v __attribute__((ext_vector_type(2)));
typedef _Float16 f16x8  __attribute__((ext_vector_type(8)));
typedef float    f32x16 __attribute__((ext_vector_type(16)));
typedef unsigned u32x4  __attribute__((ext_vector_type(4)));

__device__ __forceinline__ float fast_rsq(float x) { return __builtin_amdgcn_rsqf(x); }

// Permutation: MFMA C-row -> logical component. Chosen so each cone's
// (t,x0,x1) triple is contiguous in one lane's C-regs:
//   g0 (lanes<32) rows {0-3,8-11,16-19} hold cones 0-3; g1 rows {4-7,12-15,
//   20-23} hold cones 4-7; both groups see cones at regs (0,1,2)(3,4,5)
//   (6,7,8)(9,10,11) with t first.
__device__ const int PINV[32] = {
    0, 8, 9, 1,   4, 16, 17, 5,   10, 11, 2, 12,   18, 19, 6, 20,
    13, 3, 14, 15, 21, 7, 22, 23, 0, 0, 0, 0, 0, 0, 0, 0 };

// SOC projection, rsqrt-only form (validated R7-R14: absmax 0.031).
__device__ __forceinline__ void soc_proj(float& t, float& x0, float& x1) {
    float n2  = fmaf(x0, x0, x1 * x1);
    float n2s = fmaxf(n2, 1e-30f);
    float rsq = fast_rsq(n2s);
    float n   = n2s * rsq;
    float coef = 0.5f * (t + n);
    float sc   = coef * rsq;
    bool inside = (n <= t);
    bool below  = (n <= -t);
    float tn = inside ? t    : (below ? 0.0f : coef);
    float s  = inside ? 1.0f : (below ? 0.0f : sc);
    t = tn; x0 *= s; x1 *= s;
}

// ---------------------------------------------------------------------------
// Fused kernel, v15 — MFMA formulation.
//
// R1-R14 journey: scalar fma_mix formulations plateau at 208us, VALU-issue-
// bound (~600 serial FMAs/iter at 1 wave/SIMD; MfmaUtil 0.0 throughout).
// v15: per wave, C(24x32) = Ppi(24x24) . Lpi(24x32): 32 elements/wave, two
// lanes per element. P = 2 loop-invariant A-frags (8 VGPRs). q preloaded as
// the accumulator init. l lives in C-layout regs; the pi permutation makes
// projection lane-local and the B-operand rebuild a 6x shfl_xor(32)
// exchange. ZERO LDS in the loop. l->f16 loss killed by a residual pass
// (2 extra MFMAs, B = f16(l - f16(l))). 2048 waves = 2 waves/SIMD.
// Robustness: Ppi symmetric (A-orientation cancels); A/B k-slot maps built
// with one convention (hardware map cancels); C/D map is learn_hip-verified.
// ---------------------------------------------------------------------------
__global__ __launch_bounds__(BLOCKT, 2) void pgd_mfma(const float* __restrict__ P,
                                                      const float* __restrict__ q,
                                                      float* __restrict__ out) {
    __shared__ __align__(16) float sP[NDIM * NDIM];   // fp32 P (pow-iter + frags)
    __shared__ float sQ[EPB * (NDIM + 1)];            // q/out slab, stride 25

    const int tid   = threadIdx.x;
    const int lane  = tid & 63;
    const int wv    = tid >> 6;
    const int half  = lane >> 5;          // 0: rows {0-3,8-11,16-19}; 1: +4
    const int col   = lane & 31;          // element within the wave's tile
    const int ebase = blockIdx.x * EPB;
    const int eloc  = wv * 32 + col;      // element within block slab

    for (int i = tid; i < NDIM * NDIM; i += BLOCKT)
        sP[i] = P[i];
    for (int idx = tid; idx < EPB * NDIM; idx += BLOCKT) {
        int r = idx / NDIM, c = idx - r * NDIM;
        sQ[r * (NDIM + 1) + c] = q[ebase * NDIM + idx];
    }
    __syncthreads();

    // --- step = 1/lambda_max(P): per-wave power iteration + Rayleigh ---
    // (zero inter-block state — R2's graph-replay divergence lesson)
    float step;
    {
        float p[NDIM];
#pragma unroll
        for (int j = 0; j < NDIM; ++j)
            p[j] = (lane < NDIM) ? sP[lane * NDIM + j] : 0.0f;
        float v = (lane < NDIM) ? (1.0f + 0.01f * (float)lane) : 0.0f;

        for (int it = 0; it < POW_ITERS; ++it) {
            float w = 0.0f;
#pragma unroll
            for (int j = 0; j < NDIM; ++j)
                w = fmaf(p[j], __shfl(v, j, 64), w);
            float n2 = w * w;
#pragma unroll
            for (int off = 32; off >= 1; off >>= 1)
                n2 += __shfl_xor(n2, off, 64);
            v = w * rsqrtf(n2);
        }
        float w = 0.0f;
#pragma unroll
        for (int j = 0; j < NDIM; ++j)
            w = fmaf(p[j], __shfl(v, j, 64), w);
        float num = v * w;
        float den = v * v;
#pragma unroll
        for (int off = 32; off >= 1; off >>= 1) {
            num += __shfl_xor(num, off, 64);
            den += __shfl_xor(den, off, 64);
        }
        step = den / num;
    }

    // --- loop-invariant A-frags: A[m][k'] = P[PINV[m]][PINV[k']], f16 ---
    // k-slot convention: slot j of kstep s covers k' = 16*s + 8*half + j.
    f16x8 a0, a1;
    {
        const int m  = col;
        const int pa = PINV[m] * NDIM;    // safe even for m>=24 (masked)
#pragma unroll
        for (int j = 0; j < 8; ++j) {
            int k0 = 8 * half + j;                    // < 16 < 24 always
            float v0 = (m < 24) ? sP[pa + PINV[k0]] : 0.0f;
            a0[j] = (_Float16)v0;
            int k1 = 16 + 8 * half + j;               // 16..31
            float v1 = (m < 24 && k1 < 24) ? sP[pa + PINV[k1]] : 0.0f;
            a1[j] = (_Float16)v1;
        }
    }

    // --- q in C-layout (accumulator init) ---
    f32x16 qv;
#pragma unroll
    for (int r = 0; r < 16; ++r) qv[r] = 0.0f;
#pragma unroll
    for (int r = 0; r < 12; ++r) {
        int row = (r & 3) + 8 * (r >> 2) + 4 * half;  // C/D row map (verified)
        qv[r] = sQ[eloc * (NDIM + 1) + PINV[row]];
    }

    float l[12];
#pragma unroll
    for (int r = 0; r < 12; ++r) l[r] = 0.0f;

#pragma clang loop unroll(disable)
    for (int it = 0; it < PGD_ITERS; ++it) {
        // pack l into f16 row-pairs + f16 residual pairs
        unsigned Pw[6], Rw[6];
#pragma unroll
        for (int p = 0; p < 6; ++p) {
            _Float16 h0 = (_Float16)l[2 * p], h1 = (_Float16)l[2 * p + 1];
            half2v hv; hv[0] = h0; hv[1] = h1;
            Pw[p] = __builtin_bit_cast(unsigned, hv);
            float r0 = l[2 * p] - (float)h0;
            float r1 = l[2 * p + 1] - (float)h1;
            half2v rv; rv[0] = (_Float16)r0; rv[1] = (_Float16)r1;
            Rw[p] = __builtin_bit_cast(unsigned, rv);
        }
        // exchange with partner lane (same element, other row-group)
        unsigned eP[6], eR[6];
#pragma unroll
        for (int p = 0; p < 6; ++p) {
            eP[p] = (unsigned)__shfl_xor((int)Pw[p], 32, 64);
            eR[p] = (unsigned)__shfl_xor((int)Rw[p], 32, 64);
        }
        // B-frags: rows 0-3:g0r0-3, 4-7:g1r0-3, 8-11:g0r4-7, 12-15:g1r4-7,
        //          16-19:g0r8-11, 20-23:g1r8-11.
        u32x4 b0u, b1u, b0ru, b1ru;
        b0u.x = half ? eP[2] : Pw[0];  b0u.y = half ? eP[3] : Pw[1];
        b0u.z = half ? Pw[2] : eP[0];  b0u.w = half ? Pw[3] : eP[1];
        b1u.x = half ? 0u : Pw[4];     b1u.y = half ? 0u : Pw[5];
        b1u.z = half ? 0u : eP[4];     b1u.w = half ? 0u : eP[5];
        b0ru.x = half ? eR[2] : Rw[0]; b0ru.y = half ? eR[3] : Rw[1];
        b0ru.z = half ? Rw[2] : eR[0]; b0ru.w = half ? Rw[3] : eR[1];
        b1ru.x = half ? 0u : Rw[4];    b1ru.y = half ? 0u : Rw[5];
        b1ru.z = half ? 0u : eR[4];    b1ru.w = half ? 0u : eR[5];
        f16x8 b0  = __builtin_bit_cast(f16x8, b0u);
        f16x8 b1  = __builtin_bit_cast(f16x8, b1u);
        f16x8 b0r = __builtin_bit_cast(f16x8, b0ru);
        f16x8 b1r = __builtin_bit_cast(f16x8, b1ru);

        // g = P.l + q  (4 MFMAs: main K=0..15, K=16..23, + residual pair)
        f32x16 acc = qv;
        acc = __builtin_amdgcn_mfma_f32_32x32x16_f16(a0, b0,  acc, 0, 0, 0);
        acc = __builtin_amdgcn_mfma_f32_32x32x16_f16(a1, b1,  acc, 0, 0, 0);
        acc = __builtin_amdgcn_mfma_f32_32x32x16_f16(a0, b0r, acc, 0, 0, 0);
        acc = __builtin_amdgcn_mfma_f32_32x32x16_f16(a1, b1r, acc, 0, 0, 0);

        // y = l - step*g ; project (cones lane-local at regs 3c..3c+2)
#pragma unroll
        for (int c = 0; c < 4; ++c) {
            float t  = fmaf(-step, acc[3 * c],     l[3 * c]);
            float x0 = fmaf(-step, acc[3 * c + 1], l[3 * c + 1]);
            float x1 = fmaf(-step, acc[3 * c + 2], l[3 * c + 2]);
            soc_proj(t, x0, x1);
            l[3 * c] = t; l[3 * c + 1] = x0; l[3 * c + 2] = x1;
        }
    }

    // --- write back through sQ (disjoint comps per lane-pair) ---
#pragma unroll
    for (int r = 0; r < 12; ++r) {
        int row = (r & 3) + 8 * (r >> 2) + 4 * half;
        sQ[eloc * (NDIM + 1) + PINV[row]] = l[r];
    }
    __syncthreads();
    for (int idx = tid; idx < EPB * NDIM; idx += BLOCKT) {
        int r = idx / NDIM, c = idx - r * NDIM;
        out[ebase * NDIM + idx] = sQ[r * (NDIM + 1) + c];
    }
}

extern "C" void kernel_launch(void* const* d_in, const int* in_sizes, int n_in,
                              void* d_out, int out_size, void* d_ws, size_t ws_size,
                              hipStream_t stream) {
    const float* P = (const float*)d_in[0];   // (1, 24, 24) fp32
    const float* q = (const float*)d_in[1];   // (65536, 24, 1) fp32
    float* out     = (float*)d_out;           // (65536, 24) fp32
    (void)d_ws; (void)ws_size;

    pgd_mfma<<<BATCH / EPB, BLOCKT, 0, stream>>>(P, q, out);
}

// Round 16
// 144.316 us; speedup vs baseline: 2.7072x; 1.1232x over previous
//
#include <hip/hip_runtime.h>

#define NDIM 24          // NC*3
#define NCONE 8
#define PGD_ITERS 100
#define BATCH 65536
#define BLOCKT 256       // 4 waves/block, 32 elements per wave
#define EPB 128          // elements per block
#define POW_ITERS 48

typedef _Float16 half2v __attribute__((ext_vector_type(2)));
typedef _Float16 f16x8  __attribute__((ext_vector_type(8)));
typedef float    f32x16 __attribute__((ext_vector_type(16)));
typedef unsigned u32x4  __attribute__((ext_vector_type(4)));

__device__ __forceinline__ float fast_rsq(float x) { return __builtin_amdgcn_rsqf(x); }

// C-row -> logical component (validated R15: cones lane-local, t first):
//   lane reg r (0..11) <-> C-row (r&3)+8*(r>>2)+4*half; comp = PINV[row].
__device__ const int PINV[32] = {
    0, 8, 9, 1,   4, 16, 17, 5,   10, 11, 2, 12,   18, 19, 6, 20,
    13, 3, 14, 15, 21, 7, 22, 23, 0, 0, 0, 0, 0, 0, 0, 0 };

// k'-slot -> component (-1 = dead slot, A column zeroed, B don't-care).
// Chosen so lane half h's slots {8h..8h+7} u {16+8h..16+8h+7} hold exactly
// its OWN 12 C-resident comps in l-register order -> B-build needs no
// cross-lane exchange and no half-dependent selection (R15's 12 shfl + 24
// cndmask per iter eliminated).
__device__ const int SIG[32] = {
    0, 8, 9, 1, 10, 11, 2, 12,          // slots 0-7  = h0 l[0..7]
    4, 16, 17, 5, 18, 19, 6, 20,        // slots 8-15 = h1 l[0..7]
    13, 3, 14, 15, -1, -1, -1, -1,      // slots 16-19 = h0 l[8..11]
    21, 7, 22, 23, -1, -1, -1, -1 };    // slots 24-27 = h1 l[8..11]

// SOC projection, rsqrt-only form (validated R7-R15: absmax 0.031).
__device__ __forceinline__ void soc_proj(float& t, float& x0, float& x1) {
    float n2  = fmaf(x0, x0, x1 * x1);
    float n2s = fmaxf(n2, 1e-30f);
    float rsq = fast_rsq(n2s);
    float n   = n2s * rsq;
    float coef = 0.5f * (t + n);
    float sc   = coef * rsq;
    bool inside = (n <= t);
    bool below  = (n <= -t);
    float tn = inside ? t    : (below ? 0.0f : coef);
    float s  = inside ? 1.0f : (below ? 0.0f : sc);
    t = tn; x0 *= s; x1 *= s;
}

// ---------------------------------------------------------------------------
// Fused kernel, v16 — MFMA with sigma-slot layout (shuffle-free loop).
//
// R15 (118us): MFMA works (absmax 0.031 first try) but the per-iter
// l->B rebuild cost 12 ds_bpermute (shfl) + 24 cndmask at 2 waves/SIMD —
// chain-latency-bound, SQ_LDS_BANK_CONFLICT 590k.
// v16: K=24<32 leaves 8 dead k'-slots; SIG places each half's 12 comps in
// its own slot range -> B = pack own l into 6 words, b0=(w0..w3),
// b1=(w4,w5,x,x), IDENTICAL for both halves. Zero shfl / cndmask / LDS /
// memory ops in the loop. A-frags absorb SIG at preamble. Residual pass
// keeps l effectively f32 (P stays f16). 4 serial MFMAs/iter.
// ---------------------------------------------------------------------------
__global__ __launch_bounds__(BLOCKT, 2) void pgd_mfma(const float* __restrict__ P,
                                                      const float* __restrict__ q,
                                                      float* __restrict__ out) {
    __shared__ __align__(16) float sP[NDIM * NDIM];   // fp32 P (pow-iter + frags)
    __shared__ float sQ[EPB * (NDIM + 1)];            // q/out slab, stride 25

    const int tid   = threadIdx.x;
    const int lane  = tid & 63;
    const int wv    = tid >> 6;
    const int half  = lane >> 5;
    const int col   = lane & 31;
    const int ebase = blockIdx.x * EPB;
    const int eloc  = wv * 32 + col;

    for (int i = tid; i < NDIM * NDIM; i += BLOCKT)
        sP[i] = P[i];
    for (int idx = tid; idx < EPB * NDIM; idx += BLOCKT) {
        int r = idx / NDIM, c = idx - r * NDIM;
        sQ[r * (NDIM + 1) + c] = q[ebase * NDIM + idx];
    }
    __syncthreads();

    // --- step = 1/lambda_max(P): per-wave power iteration + Rayleigh ---
    // (zero inter-block state — R2's graph-replay divergence lesson)
    float step;
    {
        float p[NDIM];
#pragma unroll
        for (int j = 0; j < NDIM; ++j)
            p[j] = (lane < NDIM) ? sP[lane * NDIM + j] : 0.0f;
        float v = (lane < NDIM) ? (1.0f + 0.01f * (float)lane) : 0.0f;

        for (int it = 0; it < POW_ITERS; ++it) {
            float w = 0.0f;
#pragma unroll
            for (int j = 0; j < NDIM; ++j)
                w = fmaf(p[j], __shfl(v, j, 64), w);
            float n2 = w * w;
#pragma unroll
            for (int off = 32; off >= 1; off >>= 1)
                n2 += __shfl_xor(n2, off, 64);
            v = w * rsqrtf(n2);
        }
        float w = 0.0f;
#pragma unroll
        for (int j = 0; j < NDIM; ++j)
            w = fmaf(p[j], __shfl(v, j, 64), w);
        float num = v * w;
        float den = v * v;
#pragma unroll
        for (int off = 32; off >= 1; off >>= 1) {
            num += __shfl_xor(num, off, 64);
            den += __shfl_xor(den, off, 64);
        }
        step = den / num;
    }

    // --- loop-invariant A-frags: A[m][k'] = P[PINV[m]][SIG[k']] (f16) ---
    // k-slot convention (validated R15): lane half owns k = 8*half + j.
    f16x8 a0, a1;
    {
        const int m  = col;
        const int pa = PINV[m] * NDIM;
#pragma unroll
        for (int j = 0; j < 8; ++j) {
            int s0 = 8 * half + j;            // MFMA1 slots (all live)
            int c0 = SIG[s0];
            a0[j] = (_Float16)((m < 24) ? sP[pa + c0] : 0.0f);
            int s1 = 16 + 8 * half + j;       // MFMA2 slots (may be dead)
            int c1 = SIG[s1];
            a1[j] = (_Float16)((m < 24 && c1 >= 0) ? sP[pa + c1] : 0.0f);
        }
    }

    // --- q in C-layout (accumulator init) ---
    f32x16 qv;
#pragma unroll
    for (int r = 0; r < 16; ++r) qv[r] = 0.0f;
#pragma unroll
    for (int r = 0; r < 12; ++r) {
        int row = (r & 3) + 8 * (r >> 2) + 4 * half;
        qv[r] = sQ[eloc * (NDIM + 1) + PINV[row]];
    }

    float l[12];
#pragma unroll
    for (int r = 0; r < 12; ++r) l[r] = 0.0f;

#pragma clang loop unroll(disable)
    for (int it = 0; it < PGD_ITERS; ++it) {
        // pack own l (f16 main + f16 residual) — no cross-lane traffic
        unsigned w[6], rw[6];
#pragma unroll
        for (int p = 0; p < 6; ++p) {
            _Float16 h0 = (_Float16)l[2 * p], h1 = (_Float16)l[2 * p + 1];
            half2v hv; hv[0] = h0; hv[1] = h1;
            w[p] = __builtin_bit_cast(unsigned, hv);
            half2v rv;
            rv[0] = (_Float16)(l[2 * p]     - (float)h0);
            rv[1] = (_Float16)(l[2 * p + 1] - (float)h1);
            rw[p] = __builtin_bit_cast(unsigned, rv);
        }
        u32x4 b0u, b1u, b0ru, b1ru;
        b0u.x  = w[0];  b0u.y  = w[1];  b0u.z  = w[2];  b0u.w  = w[3];
        b1u.x  = w[4];  b1u.y  = w[5];  b1u.z  = w[4];  b1u.w  = w[5];   // hi: dead
        b0ru.x = rw[0]; b0ru.y = rw[1]; b0ru.z = rw[2]; b0ru.w = rw[3];
        b1ru.x = rw[4]; b1ru.y = rw[5]; b1ru.z = rw[4]; b1ru.w = rw[5];  // hi: dead
        f16x8 b0  = __builtin_bit_cast(f16x8, b0u);
        f16x8 b1  = __builtin_bit_cast(f16x8, b1u);
        f16x8 b0r = __builtin_bit_cast(f16x8, b0ru);
        f16x8 b1r = __builtin_bit_cast(f16x8, b1ru);

        // g = q + P.l  (main + residual, one accumulator chain)
        f32x16 acc = qv;
        acc = __builtin_amdgcn_mfma_f32_32x32x16_f16(a0, b0,  acc, 0, 0, 0);
        acc = __builtin_amdgcn_mfma_f32_32x32x16_f16(a1, b1,  acc, 0, 0, 0);
        acc = __builtin_amdgcn_mfma_f32_32x32x16_f16(a0, b0r, acc, 0, 0, 0);
        acc = __builtin_amdgcn_mfma_f32_32x32x16_f16(a1, b1r, acc, 0, 0, 0);

        // y = l - step*g ; project (cones lane-local at regs 3c..3c+2)
#pragma unroll
        for (int c = 0; c < 4; ++c) {
            float t  = fmaf(-step, acc[3 * c],     l[3 * c]);
            float x0 = fmaf(-step, acc[3 * c + 1], l[3 * c + 1]);
            float x1 = fmaf(-step, acc[3 * c + 2], l[3 * c + 2]);
            soc_proj(t, x0, x1);
            l[3 * c] = t; l[3 * c + 1] = x0; l[3 * c + 2] = x1;
        }
    }

    // --- write back through sQ (disjoint comps per lane-pair) ---
#pragma unroll
    for (int r = 0; r < 12; ++r) {
        int row = (r & 3) + 8 * (r >> 2) + 4 * half;
        sQ[eloc * (NDIM + 1) + PINV[row]] = l[r];
    }
    __syncthreads();
    for (int idx = tid; idx < EPB * NDIM; idx += BLOCKT) {
        int r = idx / NDIM, c = idx - r * NDIM;
        out[ebase * NDIM + idx] = sQ[r * (NDIM + 1) + c];
    }
}

extern "C" void kernel_launch(void* const* d_in, const int* in_sizes, int n_in,
                              void* d_out, int out_size, void* d_ws, size_t ws_size,
                              hipStream_t stream) {
    const float* P = (const float*)d_in[0];   // (1, 24, 24) fp32
    const float* q = (const float*)d_in[1];   // (65536, 24, 1) fp32
    float* out     = (float*)d_out;           // (65536, 24) fp32
    (void)d_ws; (void)ws_size;

    pgd_mfma<<<BATCH / EPB, BLOCKT, 0, stream>>>(P, q, out);
}